// Round 10
// baseline (15455.417 us; speedup 1.0000x reference)
//
#include <hip/hip_runtime.h>

// CustomRNN (GRU, SEQ=2048, B=256, D=512) + FC(1000) + log_softmax over batch axis.
//
// R10: TWO-STREAM INTERLEAVED persistent GRU.
//   128 blocks x 256 thr = 8 pairs x 16 col-slice blocks. Pair p (blocks bid%8==p, all on
//   XCD p) serves two independent batch streams: rows p*32..+15 (A) and p*32+16..+31 (B),
//   same 32-col slice -> same U registers. Schedule: pollA,A.p1,arrA, pollB,B.p1,arrB,
//   pollA,A.p2,arrA, pollB,B.p2,arrB. Each barrier wait is covered by a full phase of the
//   other stream -> barrier latency hidden, poll pressure ~1 RMW/barrier (R9 showed
//   parallel polls saturate the TCC line: WRITE_SIZE 98->1058 MB, dur +5%).
//   Sync primitive class UNCHANGED from the passing R3/R7: tid0 atomic-RMW arrival +
//   atomic-RMW poll (plain sc0-load polling fails: R4-R6, absmax 0.40625).

typedef unsigned short ushort_t;
typedef unsigned int uint_t;
typedef __bf16 bf16_t;
typedef bf16_t bf16x8 __attribute__((ext_vector_type(8)));
typedef float f32x4 __attribute__((ext_vector_type(4)));
typedef uint_t u32x4 __attribute__((ext_vector_type(4)));

__device__ __forceinline__ ushort_t f2bf(float f) {
  uint_t u = __float_as_uint(f);
  u += 0x7FFFu + ((u >> 16) & 1u);   // round-to-nearest-even
  return (ushort_t)(u >> 16);
}
__device__ __forceinline__ float bfu2f(uint_t h) { return __uint_as_float(h << 16); }

// TCC atomic add WITH return (waits). RMW -> always served coherently at the TCC.
__device__ __forceinline__ uint_t atom_add_ret(uint_t* p, uint_t v) {
  uint_t old;
  asm volatile("global_atomic_add %0, %1, %2, off sc0\n\t"
               "s_waitcnt vmcnt(0)"
               : "=v"(old) : "v"(p), "v"(v) : "memory");
  return old;
}
// Fire-and-forget atomic add (no return -> no wait).
__device__ __forceinline__ void atom_add_noret(uint_t* p, uint_t v) {
  asm volatile("global_atomic_add %0, %1, off" :: "v"(p), "v"(v) : "memory");
}

// ---------------------------------------------------------------- prep
__global__ __launch_bounds__(256) void prep_kernel(
    const float* __restrict__ Wz, const float* __restrict__ Wr, const float* __restrict__ Wh,
    const float* __restrict__ Uz, const float* __restrict__ Ur, const float* __restrict__ Uh,
    const float* __restrict__ bz, const float* __restrict__ buz,
    const float* __restrict__ br, const float* __restrict__ bur,
    const float* __restrict__ bh, const float* __restrict__ buh,
    ushort_t* __restrict__ UT, ushort_t* __restrict__ WT, float* __restrict__ gbias)
{
  const int idx = blockIdx.x * 256 + threadIdx.x;  // exactly 786432 threads
  {
    const int gate = idx >> 18, n = (idx >> 9) & 511, k = idx & 511;
    const float* U = (gate == 0) ? Uz : (gate == 1 ? Ur : Uh);
    UT[idx] = f2bf(U[k * 512 + n]);                 // UT[gate][n][k] = U[k][n]
  }
  {
    const int n = idx >> 9, k = idx & 511;
    const int gate = n >> 9, nn = n & 511;
    const float* W = (gate == 0) ? Wz : (gate == 1 ? Wr : Wh);
    WT[idx] = f2bf(W[k * 512 + nn]);                // WT[n][k] = W[k][n]
  }
  if (idx < 1536) {
    const int gate = idx >> 9, nn = idx & 511;
    gbias[idx] = (gate == 0) ? (bz[nn] + buz[nn])
               : (gate == 1) ? (br[nn] + bur[nn])
                             : (bh[nn] + buh[nn]);
  }
}

// ---------------------------------------------------------------- gate GEMM
__global__ __launch_bounds__(256) void gate_gemm(
    const float* __restrict__ x,
    const ushort_t* __restrict__ WT,     // [1536][512] (n-major)
    const float* __restrict__ gbias,
    ushort_t* __restrict__ gout,         // [M][1536]
    int mtiles)
{
  __shared__ ushort_t A_sh[128 * 72];
  __shared__ ushort_t B_sh[128 * 72];
  const int bid = blockIdx.x;
  int mt, nt;
  if ((mtiles & 31) == 0) {              // supertile 32 mtiles x 12 ntiles for A L2/L3 reuse
    const int sb = bid / 384;
    const int r = bid - sb * 384;
    mt = sb * 32 + (r & 31);
    nt = r >> 5;
  } else {
    mt = bid / 12;
    nt = bid - mt * 12;
  }
  const int mrow0 = mt * 128;
  const int ncol0 = nt * 128;
  const int tid = threadIdx.x;
  const int wid = tid >> 6;
  const int lane = tid & 63;
  const int wm = wid >> 1, wn = wid & 1;
  const int l15 = lane & 15, l4 = lane >> 4;

  const f32x4 vzero = {0.f, 0.f, 0.f, 0.f};
  f32x4 acc[4][4];
#pragma unroll
  for (int m = 0; m < 4; ++m)
#pragma unroll
    for (int n = 0; n < 4; ++n) acc[m][n] = vzero;

  const int ar = tid >> 4, ak = tid & 15;
  const int bn = tid >> 3, bk = tid & 7;

  for (int ks = 0; ks < 8; ++ks) {
    if (ks) __syncthreads();
    const int k0 = ks * 64;
#pragma unroll
    for (int p = 0; p < 8; ++p) {
      const int r = p * 16 + ar;
      const float4 v = *(const float4*)&x[(size_t)(mrow0 + r) * 512 + (k0 + ak * 4)];
      ushort4 hv;
      hv.x = f2bf(v.x); hv.y = f2bf(v.y); hv.z = f2bf(v.z); hv.w = f2bf(v.w);
      *(ushort4*)&A_sh[r * 72 + ak * 4] = hv;
    }
#pragma unroll
    for (int p = 0; p < 4; ++p) {
      const int n = p * 32 + bn;
      *(uint4*)&B_sh[n * 72 + bk * 8] =
          *(const uint4*)&WT[(size_t)(ncol0 + n) * 512 + (k0 + bk * 8)];
    }
    __syncthreads();
#pragma unroll
    for (int kk = 0; kk < 2; ++kk) {
      bf16x8 a[4], b[4];
#pragma unroll
      for (int m = 0; m < 4; ++m)
        a[m] = *(const bf16x8*)&A_sh[(wm * 64 + m * 16 + l15) * 72 + kk * 32 + l4 * 8];
#pragma unroll
      for (int n = 0; n < 4; ++n)
        b[n] = *(const bf16x8*)&B_sh[(wn * 64 + n * 16 + l15) * 72 + kk * 32 + l4 * 8];
#pragma unroll
      for (int m = 0; m < 4; ++m)
#pragma unroll
        for (int n = 0; n < 4; ++n)
          acc[m][n] = __builtin_amdgcn_mfma_f32_16x16x32_bf16(a[m], b[n], acc[m][n], 0, 0, 0);
    }
  }
#pragma unroll
  for (int n = 0; n < 4; ++n) {
    const int gcol = ncol0 + wn * 64 + n * 16 + l15;
    const float bv = gbias[gcol];
#pragma unroll
    for (int m = 0; m < 4; ++m) {
      const int grow = mrow0 + wm * 64 + m * 16 + l4 * 4;
#pragma unroll
      for (int q = 0; q < 4; ++q)
        gout[(size_t)(grow + q) * 1536 + gcol] = f2bf(acc[m][n][q] + bv);
    }
  }
}

// Stage a [16 rows][512] bf16 tile (16 KB) from global (shared L2) into LDS.
// sc0 loads bypass the (possibly stale) L1; ends with vmcnt(0).
__device__ __forceinline__ void stage16x512(const ushort_t* __restrict__ src,
                                            ushort_t* dst_lds, int tid) {
  const ushort_t* p[4];
#pragma unroll
  for (int k = 0; k < 4; ++k) {
    const int idx = tid + (k << 8);
    const int r = idx >> 6, kc = idx & 63;
    p[k] = src + ((r << 9) + kc * 8);
  }
  u32x4 v0, v1, v2, v3;
  asm volatile(
      "global_load_dwordx4 %0, %4, off sc0\n\t"
      "global_load_dwordx4 %1, %5, off sc0\n\t"
      "global_load_dwordx4 %2, %6, off sc0\n\t"
      "global_load_dwordx4 %3, %7, off sc0\n\t"
      "s_waitcnt vmcnt(0)"
      : "=&v"(v0), "=&v"(v1), "=&v"(v2), "=&v"(v3)
      : "v"(p[0]), "v"(p[1]), "v"(p[2]), "v"(p[3])
      : "memory");
#pragma unroll
  for (int k = 0; k < 4; ++k) {
    const int idx = tid + (k << 8);
    const int r = idx >> 6, kc = idx & 63;
    *(u32x4*)&dst_lds[r * 520 + kc * 8] = (k == 0) ? v0 : (k == 1) ? v1 : (k == 2) ? v2 : v3;
  }
}

// ---------------------------------------------------------------- persistent GRU recurrence
__global__ __launch_bounds__(256, 1) void gru_rec(
    const ushort_t* __restrict__ UT,     // [3][512 n][512 k] bf16
    const ushort_t* __restrict__ gates,  // [Tc][256][1536] bf16
    ushort_t* __restrict__ h_buf,        // [256][512] bf16
    ushort_t* __restrict__ rh_buf,       // [256][512] bf16
    float* __restrict__ h_state,         // [256][512] fp32
    uint_t* __restrict__ bars,           // 8 pairs x 2 counters (64B apart)
    int Tc, int first)
{
  __shared__ ushort_t h_st[16 * 520];
  __shared__ float z_shA[512], z_shB[512];
  __shared__ float hownA[512], hownB[512];
  __shared__ float red[512];
  __shared__ int s_dead;

  const int tid = threadIdx.x;
  const int bid = blockIdx.x;
  const int p = bid & 7;        // pair id -> XCD p
  const int j = bid >> 3;       // col slice [0,16)
  const int wid = tid >> 6;
  const int lane = tid & 63;
  const int l15 = lane & 15;
  const int l4 = lane >> 4;
  if (tid == 0) s_dead = 0;

  const int row0A = p * 32;
  const int row0B = p * 32 + 16;
  uint_t* ctrA = bars + p * 32;        // own 64B line
  uint_t* ctrB = bars + p * 32 + 16;   // next 64B line

  const int p1gate = wid >> 1;  // phase1: waves 0,1 -> z ; waves 2,3 -> r
  const int p1nt = wid & 1;
  const int p2nt = wid >> 1;    // phase2 subtile
  const int p2kh = wid & 1;     // phase2 K half

  // U fragments persistent in registers (shared by both streams)
  bf16x8 UB[16];
  {
    const size_t base = (size_t)((p1gate << 9) + j * 32 + p1nt * 16 + l15) * 512 + (size_t)(l4 * 8);
#pragma unroll
    for (int kk = 0; kk < 16; ++kk) UB[kk] = *(const bf16x8*)&UT[base + (size_t)kk * 32];
  }
  bf16x8 UH[8];
  {
    const size_t base = (size_t)(1024 + j * 32 + p2nt * 16 + l15) * 512 + (size_t)(p2kh * 256 + l4 * 8);
#pragma unroll
    for (int kk = 0; kk < 8; ++kk) UH[kk] = *(const bf16x8*)&UT[base + (size_t)kk * 32];
  }

  if (first) {
    for (int i = tid; i < 512; i += 256) {
      const int r = i >> 5, c = i & 31;
      h_buf[((size_t)(row0A + r) << 9) + j * 32 + c] = 0;
      h_buf[((size_t)(row0B + r) << 9) + j * 32 + c] = 0;
      hownA[i] = 0.f;
      hownB[i] = 0.f;
    }
  } else {
    for (int i = tid; i < 512; i += 256) {
      const int r = i >> 5, c = i & 31;
      hownA[i] = h_state[((size_t)(row0A + r) << 9) + j * 32 + c];
      hownB[i] = h_state[((size_t)(row0B + r) << 9) + j * 32 + c];
    }
  }
  // init barrier (arrive both streams' counters)
  asm volatile("s_waitcnt vmcnt(0)" ::: "memory");
  __syncthreads();
  if (tid == 0) { atom_add_noret(ctrA, 1u); atom_add_noret(ctrB, 1u); }
  uint_t tgtA = 16, tgtB = 16;

  const int colg1 = (p1gate << 9) + j * 32 + p1nt * 16 + l15;  // phase1 gate col (abs)
  const int colg2 = 1024 + j * 32 + p2nt * 16 + l15;           // phase2 gate col (abs)

  // prime step-0 gates for both streams (plain compiler-tracked loads)
  uint_t n1uA[4], n2uA[4], n1uB[4], n2uB[4];
  {
    const size_t gbA = (size_t)(row0A + l4 * 4) * 1536;
    const size_t gbB = (size_t)(row0B + l4 * 4) * 1536;
#pragma unroll
    for (int q = 0; q < 4; ++q) {
      n1uA[q] = gates[gbA + (size_t)q * 1536 + colg1];
      n2uA[q] = gates[gbA + (size_t)q * 1536 + colg2];
      n1uB[q] = gates[gbB + (size_t)q * 1536 + colg1];
      n2uB[q] = gates[gbB + (size_t)q * 1536 + colg2];
    }
  }

#define POLL(ctr, tgt)                                              \
  if (tid == 0) {                                                   \
    int cnt_ = 0;                                                   \
    for (;;) {                                                      \
      const uint_t seen_ = atom_add_ret(ctr, 0u);                   \
      if (seen_ >= (tgt)) break;                                    \
      __builtin_amdgcn_s_sleep(1);                                  \
      if (++cnt_ > (1 << 15)) { s_dead = 1; break; }                \
    }                                                               \
  }                                                                 \
  __syncthreads();                                                  \
  if (s_dead) break;

#define ARRIVE(ctr, tgt)                                            \
  asm volatile("s_waitcnt vmcnt(0)" ::: "memory");                  \
  __syncthreads();                                                  \
  if (tid == 0) atom_add_noret(ctr, 1u);                            \
  (tgt) += 16;

#define PHASE1(S)                                                              \
  POLL(ctr##S, tgt##S);                                                        \
  stage16x512(h_buf + ((size_t)row0##S << 9), h_st, tid);                      \
  __syncthreads();                                                             \
  {                                                                            \
    const ushort_t* ap = &h_st[l15 * 520 + l4 * 8];                            \
    f32x4 a0 = {0.f, 0.f, 0.f, 0.f}, a1 = {0.f, 0.f, 0.f, 0.f};                \
    _Pragma("unroll")                                                          \
    for (int kk = 0; kk < 16; kk += 2) {                                       \
      a0 = __builtin_amdgcn_mfma_f32_16x16x32_bf16(*(const bf16x8*)(ap + kk * 32), UB[kk], a0, 0, 0, 0); \
      a1 = __builtin_amdgcn_mfma_f32_16x16x32_bf16(*(const bf16x8*)(ap + kk * 32 + 32), UB[kk + 1], a1, 0, 0, 0); \
    }                                                                          \
    const f32x4 acc = a0 + a1;                                                 \
    const int lc = p1nt * 16 + l15;                                            \
    _Pragma("unroll")                                                          \
    for (int q = 0; q < 4; ++q) {                                              \
      const int row = l4 * 4 + q;                                              \
      const float pre = acc[q] + bfu2f(n1u##S[q]);                             \
      const float s = 1.f / (1.f + __expf(-pre));                              \
      if (p1gate == 0) z_sh##S[row * 32 + lc] = s;                             \
      else rh_buf[((size_t)(row0##S + row) << 9) + j * 32 + lc] =              \
               f2bf(s * hown##S[row * 32 + lc]);                               \
    }                                                                          \
  }                                                                            \
  ARRIVE(ctr##S, tgt##S);

#define PHASE2(S)                                                              \
  POLL(ctr##S, tgt##S);                                                        \
  stage16x512(rh_buf + ((size_t)row0##S << 9), h_st, tid);                     \
  __syncthreads();                                                             \
  {                                                                            \
    uint_t c2_[4] = {n2u##S[0], n2u##S[1], n2u##S[2], n2u##S[3]};              \
    if (tt + 1 < Tc) {                                                         \
      const size_t gb = ((size_t)(tt + 1) * 256 + row0##S + l4 * 4) * 1536;    \
      _Pragma("unroll")                                                        \
      for (int q = 0; q < 4; ++q) {                                            \
        n1u##S[q] = gates[gb + (size_t)q * 1536 + colg1];                      \
        n2u##S[q] = gates[gb + (size_t)q * 1536 + colg2];                      \
      }                                                                        \
    }                                                                          \
    const ushort_t* ap = &h_st[l15 * 520 + p2kh * 256 + l4 * 8];               \
    f32x4 a0 = {0.f, 0.f, 0.f, 0.f}, a1 = {0.f, 0.f, 0.f, 0.f};                \
    _Pragma("unroll")                                                          \
    for (int kk = 0; kk < 8; kk += 2) {                                        \
      a0 = __builtin_amdgcn_mfma_f32_16x16x32_bf16(*(const bf16x8*)(ap + kk * 32), UH[kk], a0, 0, 0, 0); \
      a1 = __builtin_amdgcn_mfma_f32_16x16x32_bf16(*(const bf16x8*)(ap + kk * 32 + 32), UH[kk + 1], a1, 0, 0, 0); \
    }                                                                          \
    const f32x4 acc = a0 + a1;                                                 \
    if (p2kh == 1) {                                                           \
      _Pragma("unroll")                                                        \
      for (int q = 0; q < 4; ++q) red[p2nt * 256 + (l4 * 4 + q) * 16 + l15] = acc[q]; \
    }                                                                          \
    __syncthreads();                                                           \
    if (p2kh == 0) {                                                           \
      const int lc = p2nt * 16 + l15;                                          \
      _Pragma("unroll")                                                        \
      for (int q = 0; q < 4; ++q) {                                            \
        const int row = l4 * 4 + q;                                            \
        const float dot = acc[q] + red[p2nt * 256 + row * 16 + l15];           \
        float pre = dot + bfu2f(c2_[q]);                                       \
        pre = fminf(15.f, fmaxf(-15.f, pre));                                  \
        const float e = __expf(2.f * pre);                                     \
        const float th = (e - 1.f) / (e + 1.f);                                \
        const float z = z_sh##S[row * 32 + lc];                                \
        const float hold = hown##S[row * 32 + lc];                             \
        const float hnew = (1.f - z) * hold + z * th;                          \
        hown##S[row * 32 + lc] = hnew;                                         \
        h_buf[((size_t)(row0##S + row) << 9) + j * 32 + lc] = f2bf(hnew);      \
        if (tt == Tc - 1) h_state[((size_t)(row0##S + row) << 9) + j * 32 + lc] = hnew; \
      }                                                                        \
    }                                                                          \
  }                                                                            \
  ARRIVE(ctr##S, tgt##S);

  for (int tt = 0; tt < Tc; ++tt) {
    PHASE1(A);
    PHASE1(B);
    PHASE2(A);
    PHASE2(B);
  }
#undef POLL
#undef ARRIVE
#undef PHASE1
#undef PHASE2
}

// ---------------------------------------------------------------- FC
__global__ __launch_bounds__(256) void fc_kernel(
    const float* __restrict__ h, const float* __restrict__ Wfc,
    const float* __restrict__ bfc, float* __restrict__ logits)
{
  __shared__ float hsh[16][520];
  const int tid = threadIdx.x;
  const int by = blockIdx.y;
  {
    const int r = tid >> 4, seg = tid & 15;
    const float* src = &h[(size_t)(by * 16 + r) * 512 + seg * 32];
#pragma unroll
    for (int i = 0; i < 8; ++i) {
      float4 v = *(const float4*)&src[i * 4];
      v.x = fmaxf(v.x, 0.f); v.y = fmaxf(v.y, 0.f);
      v.z = fmaxf(v.z, 0.f); v.w = fmaxf(v.w, 0.f);
      *(float4*)&hsh[r][seg * 32 + i * 4] = v;
    }
  }
  __syncthreads();
  const int c = tid & 63, rq = tid >> 6;
  const int gc = blockIdx.x * 64 + c;
  if (gc >= 1000) return;
  float acc0 = 0.f, acc1 = 0.f, acc2 = 0.f, acc3 = 0.f;
  for (int k = 0; k < 512; ++k) {
    const float w = Wfc[(size_t)k * 1000 + gc];
    acc0 += hsh[rq * 4 + 0][k] * w;
    acc1 += hsh[rq * 4 + 1][k] * w;
    acc2 += hsh[rq * 4 + 2][k] * w;
    acc3 += hsh[rq * 4 + 3][k] * w;
  }
  const float bv = bfc[gc];
  const int r0 = by * 16 + rq * 4;
  logits[(size_t)(r0 + 0) * 1000 + gc] = acc0 + bv;
  logits[(size_t)(r0 + 1) * 1000 + gc] = acc1 + bv;
  logits[(size_t)(r0 + 2) * 1000 + gc] = acc2 + bv;
  logits[(size_t)(r0 + 3) * 1000 + gc] = acc3 + bv;
}

// ---------------------------------------------------------------- log_softmax over batch
__global__ __launch_bounds__(256) void lsm_kernel(const float* __restrict__ logits,
                                                  float* __restrict__ out)
{
  const int c = blockIdx.x, tid = threadIdx.x;
  const int wid = tid >> 6, lane = tid & 63;
  __shared__ float red[8];
  const float v = logits[(size_t)tid * 1000 + c];
  float m = v;
#pragma unroll
  for (int o = 32; o >= 1; o >>= 1) m = fmaxf(m, __shfl_xor(m, o));
  if (lane == 0) red[wid] = m;
  __syncthreads();
  m = fmaxf(fmaxf(red[0], red[1]), fmaxf(red[2], red[3]));
  float s = __expf(v - m);
#pragma unroll
  for (int o = 32; o >= 1; o >>= 1) s += __shfl_xor(s, o);
  if (lane == 0) red[4 + wid] = s;
  __syncthreads();
  s = red[4] + red[5] + red[6] + red[7];
  out[(size_t)tid * 1000 + c] = (v - m) - __logf(s);
}

// ---------------------------------------------------------------- launch
extern "C" void kernel_launch(void* const* d_in, const int* in_sizes, int n_in,
                              void* d_out, int out_size, void* d_ws, size_t ws_size,
                              hipStream_t stream) {
  (void)in_sizes; (void)n_in; (void)out_size;
  const float* x   = (const float*)d_in[0];
  const float* Wz  = (const float*)d_in[1];
  const float* bz  = (const float*)d_in[2];
  const float* Uz  = (const float*)d_in[3];
  const float* buz = (const float*)d_in[4];
  const float* Wr  = (const float*)d_in[5];
  const float* br  = (const float*)d_in[6];
  const float* Ur  = (const float*)d_in[7];
  const float* bur = (const float*)d_in[8];
  const float* Wh  = (const float*)d_in[9];
  const float* bh  = (const float*)d_in[10];
  const float* Uh  = (const float*)d_in[11];
  const float* buh = (const float*)d_in[12];
  const float* Wfc = (const float*)d_in[13];
  const float* bfc = (const float*)d_in[14];
  float* out = (float*)d_out;
  char* ws = (char*)d_ws;

  ushort_t* UT     = (ushort_t*)(ws + 0);        // 1572864 B
  ushort_t* WT     = (ushort_t*)(ws + 1572864);  // 1572864 B
  float*    gbias  = (float*)(ws + 3145728);     // 6144 B
  ushort_t* h_buf  = (ushort_t*)(ws + 3151872);  // 262144 B
  ushort_t* rh_buf = (ushort_t*)(ws + 3414016);  // 262144 B
  float*    hstate = (float*)(ws + 3676160);     // 524288 B
  float*    logits = (float*)(ws + 4200448);     // 1024000 B (256x1000)
  uint_t*   bars   = (uint_t*)(ws + 5224448);    // 4096 B (8 pairs x 128B)
  ushort_t* gates  = (ushort_t*)(ws + 5228544);  // Tc*256*1536*2 B

  const size_t fixed = 5228544;
  const size_t per_step = (size_t)256 * 1536 * 2;
  int Tc_max = 2048;
  if (ws_size < fixed + (size_t)2048 * per_step) {
    const size_t avail = (ws_size > fixed) ? (ws_size - fixed) : 0;
    Tc_max = (int)(avail / per_step);
    Tc_max &= ~15;             // keep mtiles % 32 == 0 for the GEMM supertile swizzle
    if (Tc_max < 16) Tc_max = 16;
  }

  prep_kernel<<<3072, 256, 0, stream>>>(Wz, Wr, Wh, Uz, Ur, Uh,
                                        bz, buz, br, bur, bh, buh, UT, WT, gbias);

  int done = 0;
  while (done < 2048) {
    const int Tc = (2048 - done < Tc_max) ? (2048 - done) : Tc_max;
    const int mtiles = Tc * 2;  // Tc*256/128
    gate_gemm<<<mtiles * 12, 256, 0, stream>>>(x + (size_t)done * 256 * 512, WT, gbias, gates, mtiles);
    hipMemsetAsync(bars, 0, 4096, stream);
    gru_rec<<<128, 256, 0, stream>>>(UT, gates, h_buf, rh_buf, hstate, bars, Tc, done == 0 ? 1 : 0);
    done += Tc;
  }
  fc_kernel<<<dim3(16, 16), 256, 0, stream>>>(hstate, Wfc, bfc, logits);
  lsm_kernel<<<1000, 256, 0, stream>>>(logits, out);
}

// Round 11
// 9924.110 us; speedup vs baseline: 1.5574x; 1.5574x over previous
//
#include <hip/hip_runtime.h>

// CustomRNN (GRU, SEQ=2048, B=256, D=512) + FC(1000) + log_softmax over batch axis.
//
// R11 = R7 anchor (PASSING: 256 blocks x 256 thr, 16 groups x 16 col-slices, serial
// atomic-RMW barrier) + two surgical changes, each from a PASSING round:
//  (1) [from R9, passing] gate prefetch for t+1 = PLAIN compiler-tracked loads at
//      phase-2 start: they land under the ~1500cy of MFMA/epilogue, so the barrier-2
//      poll's vmcnt(0) and the next stage's vmcnt(0) carry ZERO outstanding loads.
//      R7 issued raw loads right before the poll -> every poll drained ~900cy of HBM
//      (in-order vmcnt accounting). R9's regression was its parallel poll (not this),
//      which is NOT carried here.
//  (2) stage chunk rotation by j*64: the 16 blocks of a group broadcast-read the same
//      16KB h tile simultaneously; rotating start offsets spreads the first-touch
//      lines across L2 banks instead of 16 requesters hitting the same line at once.
// Sync primitive class UNCHANGED (R3/R7-proven): tid0 atomic-RMW arrival +
// atomic-RMW poll. (Load-based polling fails: R4-R6, absmax 0.40625.)

typedef unsigned short ushort_t;
typedef unsigned int uint_t;
typedef __bf16 bf16_t;
typedef bf16_t bf16x8 __attribute__((ext_vector_type(8)));
typedef float f32x4 __attribute__((ext_vector_type(4)));
typedef uint_t u32x4 __attribute__((ext_vector_type(4)));

__device__ __forceinline__ ushort_t f2bf(float f) {
  uint_t u = __float_as_uint(f);
  u += 0x7FFFu + ((u >> 16) & 1u);   // round-to-nearest-even
  return (ushort_t)(u >> 16);
}
__device__ __forceinline__ float bfu2f(uint_t h) { return __uint_as_float(h << 16); }

// TCC atomic add WITH return (waits). RMW -> always served coherently at the TCC.
__device__ __forceinline__ uint_t atom_add_ret(uint_t* p, uint_t v) {
  uint_t old;
  asm volatile("global_atomic_add %0, %1, %2, off sc0\n\t"
               "s_waitcnt vmcnt(0)"
               : "=v"(old) : "v"(p), "v"(v) : "memory");
  return old;
}
// Fire-and-forget atomic add (no return -> no wait).
__device__ __forceinline__ void atom_add_noret(uint_t* p, uint_t v) {
  asm volatile("global_atomic_add %0, %1, off" :: "v"(p), "v"(v) : "memory");
}

// ---------------------------------------------------------------- prep
__global__ __launch_bounds__(256) void prep_kernel(
    const float* __restrict__ Wz, const float* __restrict__ Wr, const float* __restrict__ Wh,
    const float* __restrict__ Uz, const float* __restrict__ Ur, const float* __restrict__ Uh,
    const float* __restrict__ bz, const float* __restrict__ buz,
    const float* __restrict__ br, const float* __restrict__ bur,
    const float* __restrict__ bh, const float* __restrict__ buh,
    ushort_t* __restrict__ UT, ushort_t* __restrict__ WT, float* __restrict__ gbias)
{
  const int idx = blockIdx.x * 256 + threadIdx.x;  // exactly 786432 threads
  {
    const int gate = idx >> 18, n = (idx >> 9) & 511, k = idx & 511;
    const float* U = (gate == 0) ? Uz : (gate == 1 ? Ur : Uh);
    UT[idx] = f2bf(U[k * 512 + n]);                 // UT[gate][n][k] = U[k][n]
  }
  {
    const int n = idx >> 9, k = idx & 511;
    const int gate = n >> 9, nn = n & 511;
    const float* W = (gate == 0) ? Wz : (gate == 1 ? Wr : Wh);
    WT[idx] = f2bf(W[k * 512 + nn]);                // WT[n][k] = W[k][n]
  }
  if (idx < 1536) {
    const int gate = idx >> 9, nn = idx & 511;
    gbias[idx] = (gate == 0) ? (bz[nn] + buz[nn])
               : (gate == 1) ? (br[nn] + bur[nn])
                             : (bh[nn] + buh[nn]);
  }
}

// ---------------------------------------------------------------- gate GEMM
__global__ __launch_bounds__(256) void gate_gemm(
    const float* __restrict__ x,
    const ushort_t* __restrict__ WT,     // [1536][512] (n-major)
    const float* __restrict__ gbias,
    ushort_t* __restrict__ gout,         // [M][1536]
    int mtiles)
{
  __shared__ ushort_t A_sh[128 * 72];
  __shared__ ushort_t B_sh[128 * 72];
  const int bid = blockIdx.x;
  int mt, nt;
  if ((mtiles & 31) == 0) {              // supertile 32 mtiles x 12 ntiles for A L2/L3 reuse
    const int sb = bid / 384;
    const int r = bid - sb * 384;
    mt = sb * 32 + (r & 31);
    nt = r >> 5;
  } else {
    mt = bid / 12;
    nt = bid - mt * 12;
  }
  const int mrow0 = mt * 128;
  const int ncol0 = nt * 128;
  const int tid = threadIdx.x;
  const int wid = tid >> 6;
  const int lane = tid & 63;
  const int wm = wid >> 1, wn = wid & 1;
  const int l15 = lane & 15, l4 = lane >> 4;

  const f32x4 vzero = {0.f, 0.f, 0.f, 0.f};
  f32x4 acc[4][4];
#pragma unroll
  for (int m = 0; m < 4; ++m)
#pragma unroll
    for (int n = 0; n < 4; ++n) acc[m][n] = vzero;

  const int ar = tid >> 4, ak = tid & 15;
  const int bn = tid >> 3, bk = tid & 7;

  for (int ks = 0; ks < 8; ++ks) {
    if (ks) __syncthreads();
    const int k0 = ks * 64;
#pragma unroll
    for (int p = 0; p < 8; ++p) {
      const int r = p * 16 + ar;
      const float4 v = *(const float4*)&x[(size_t)(mrow0 + r) * 512 + (k0 + ak * 4)];
      ushort4 hv;
      hv.x = f2bf(v.x); hv.y = f2bf(v.y); hv.z = f2bf(v.z); hv.w = f2bf(v.w);
      *(ushort4*)&A_sh[r * 72 + ak * 4] = hv;
    }
#pragma unroll
    for (int p = 0; p < 4; ++p) {
      const int n = p * 32 + bn;
      *(uint4*)&B_sh[n * 72 + bk * 8] =
          *(const uint4*)&WT[(size_t)(ncol0 + n) * 512 + (k0 + bk * 8)];
    }
    __syncthreads();
#pragma unroll
    for (int kk = 0; kk < 2; ++kk) {
      bf16x8 a[4], b[4];
#pragma unroll
      for (int m = 0; m < 4; ++m)
        a[m] = *(const bf16x8*)&A_sh[(wm * 64 + m * 16 + l15) * 72 + kk * 32 + l4 * 8];
#pragma unroll
      for (int n = 0; n < 4; ++n)
        b[n] = *(const bf16x8*)&B_sh[(wn * 64 + n * 16 + l15) * 72 + kk * 32 + l4 * 8];
#pragma unroll
      for (int m = 0; m < 4; ++m)
#pragma unroll
        for (int n = 0; n < 4; ++n)
          acc[m][n] = __builtin_amdgcn_mfma_f32_16x16x32_bf16(a[m], b[n], acc[m][n], 0, 0, 0);
    }
  }
#pragma unroll
  for (int n = 0; n < 4; ++n) {
    const int gcol = ncol0 + wn * 64 + n * 16 + l15;
    const float bv = gbias[gcol];
#pragma unroll
    for (int m = 0; m < 4; ++m) {
      const int grow = mrow0 + wm * 64 + m * 16 + l4 * 4;
#pragma unroll
      for (int q = 0; q < 4; ++q)
        gout[(size_t)(grow + q) * 1536 + gcol] = f2bf(acc[m][n][q] + bv);
    }
  }
}

// ---------------------------------------------------------------- XCD-local group barrier
// Monotone counter; arrival = non-blocking add, wait = poll RMW until ctr >= 16*n.
__device__ __forceinline__ bool group_barrier(uint_t* ctr, uint_t target, int tid, int* s_dead) {
  asm volatile("s_waitcnt vmcnt(0)" ::: "memory");  // own stores committed to L2
  __syncthreads();                                   // all waves drained
  if (tid == 0) {
    atom_add_noret(ctr, 1u);
    int cnt = 0;
    for (;;) {
      const uint_t seen = atom_add_ret(ctr, 0u);     // RMW -> always served at TCC
      if (seen >= target) break;
      __builtin_amdgcn_s_sleep(1);
      if (++cnt > (1 << 15)) { *s_dead = 1; break; } // co-location broken: fast-fail
    }
  }
  __syncthreads();
  return *s_dead != 0;
}

// Stage a [16 rows][512] bf16 tile (16 KB) from global (shared L2) into LDS.
// sc0 loads bypass the (possibly stale) L1; ends with vmcnt(0).
// Chunk index rotated by j*64 so the 16 blocks of a group start on different
// L2 lines of the shared tile (avoids 16 simultaneous requesters per line).
__device__ __forceinline__ void stage16x512(const ushort_t* __restrict__ src, int g, int j,
                                            ushort_t* dst_lds, int tid) {
  const ushort_t* p[4];
  int ridx[4];
#pragma unroll
  for (int k = 0; k < 4; ++k) {
    const int idx = (tid + (k << 8) + j * 64) & 1023;
    ridx[k] = idx;
    const int r = idx >> 6, kc = idx & 63;
    p[k] = src + (((g * 16 + r) << 9) + kc * 8);
  }
  u32x4 v0, v1, v2, v3;
  asm volatile(
      "global_load_dwordx4 %0, %4, off sc0\n\t"
      "global_load_dwordx4 %1, %5, off sc0\n\t"
      "global_load_dwordx4 %2, %6, off sc0\n\t"
      "global_load_dwordx4 %3, %7, off sc0\n\t"
      "s_waitcnt vmcnt(0)"
      : "=&v"(v0), "=&v"(v1), "=&v"(v2), "=&v"(v3)
      : "v"(p[0]), "v"(p[1]), "v"(p[2]), "v"(p[3])
      : "memory");
#pragma unroll
  for (int k = 0; k < 4; ++k) {
    const int r = ridx[k] >> 6, kc = ridx[k] & 63;
    *(u32x4*)&dst_lds[r * 520 + kc * 8] = (k == 0) ? v0 : (k == 1) ? v1 : (k == 2) ? v2 : v3;
  }
}

// ---------------------------------------------------------------- persistent GRU recurrence
__global__ __launch_bounds__(256, 1) void gru_rec(
    const ushort_t* __restrict__ UT,     // [3][512 n][512 k] bf16
    const ushort_t* __restrict__ gates,  // [Tc][256][1536] bf16
    ushort_t* __restrict__ h_buf,        // [256][512] bf16
    ushort_t* __restrict__ rh_buf,       // [256][512] bf16
    float* __restrict__ h_state,         // [256][512] fp32
    uint_t* __restrict__ bars,
    int Tc, int first)
{
  __shared__ ushort_t h_st[16 * 520];
  __shared__ float z_sh[512];
  __shared__ float hown[512];
  __shared__ float red[512];
  __shared__ int s_dead;

  const int tid = threadIdx.x;
  const int bid = blockIdx.x;
  const int g = bid & 15;
  const int j = bid >> 4;
  const int wid = tid >> 6;
  const int lane = tid & 63;
  const int l15 = lane & 15;
  const int l4 = lane >> 4;
  if (tid == 0) s_dead = 0;

  uint_t* ctr = bars + g * 64;          // one counter per group, own cacheline
  uint_t nbar = 0;

  const int p1gate = wid >> 1;  // phase1: waves 0,1 -> z ; waves 2,3 -> r
  const int p1nt = wid & 1;
  const int p2nt = wid >> 1;    // phase2 subtile
  const int p2kh = wid & 1;     // phase2 K half

  // U fragments persistent in registers
  bf16x8 UB[16];
  {
    const size_t base = (size_t)((p1gate << 9) + j * 32 + p1nt * 16 + l15) * 512 + (size_t)(l4 * 8);
#pragma unroll
    for (int kk = 0; kk < 16; ++kk) UB[kk] = *(const bf16x8*)&UT[base + (size_t)kk * 32];
  }
  bf16x8 UH[8];
  {
    const size_t base = (size_t)(1024 + j * 32 + p2nt * 16 + l15) * 512 + (size_t)(p2kh * 256 + l4 * 8);
#pragma unroll
    for (int kk = 0; kk < 8; ++kk) UH[kk] = *(const bf16x8*)&UT[base + (size_t)kk * 32];
  }

  if (first) {
    for (int i = tid; i < 512; i += 256) {
      const int r = i >> 5, c = i & 31;
      h_buf[((g * 16 + r) << 9) + j * 32 + c] = 0;
      hown[i] = 0.f;
    }
  } else {
    for (int i = tid; i < 512; i += 256) {
      const int r = i >> 5, c = i & 31;
      hown[i] = h_state[((g * 16 + r) << 9) + j * 32 + c];
    }
  }
  if (group_barrier(ctr, (++nbar) * 16, tid, &s_dead)) return;

  const int colg1 = j * 32 + p1nt * 16 + l15;
  const int colg2 = j * 32 + p2nt * 16 + l15;

  // gate pipeline: n* prefetched as PLAIN compiler-tracked loads at phase-2 start
  // of the previous step; copied to c* at phase-1 top (compiler inserts the wait).
  uint_t c1u[4], c2u[4], n1u[4], n2u[4];
  {
    const size_t gb = (size_t)(g * 16) * 1536;
#pragma unroll
    for (int q = 0; q < 4; ++q) {
      n1u[q] = gates[gb + (size_t)(l4 * 4 + q) * 1536 + (p1gate << 9) + colg1];
      n2u[q] = gates[gb + (size_t)(l4 * 4 + q) * 1536 + 1024 + colg2];
    }
  }

  for (int tt = 0; tt < Tc; ++tt) {
    // ---- phase 1: z, r from h
    stage16x512(h_buf, g, j, h_st, tid);
    __syncthreads();
#pragma unroll
    for (int q = 0; q < 4; ++q) { c1u[q] = n1u[q]; c2u[q] = n2u[q]; }
    {
      const ushort_t* ap = &h_st[l15 * 520 + l4 * 8];
      f32x4 a0 = {0.f, 0.f, 0.f, 0.f}, a1 = {0.f, 0.f, 0.f, 0.f};
#pragma unroll
      for (int kk = 0; kk < 16; kk += 2) {
        a0 = __builtin_amdgcn_mfma_f32_16x16x32_bf16(*(const bf16x8*)(ap + kk * 32), UB[kk], a0, 0, 0, 0);
        a1 = __builtin_amdgcn_mfma_f32_16x16x32_bf16(*(const bf16x8*)(ap + kk * 32 + 32), UB[kk + 1], a1, 0, 0, 0);
      }
      const f32x4 acc = a0 + a1;
      const int lc = p1nt * 16 + l15;
#pragma unroll
      for (int q = 0; q < 4; ++q) {
        const int row = l4 * 4 + q;
        const float pre = acc[q] + bfu2f(c1u[q]);
        const float s = 1.f / (1.f + __expf(-pre));
        if (p1gate == 0) z_sh[row * 32 + lc] = s;
        else rh_buf[((g * 16 + row) << 9) + j * 32 + lc] = f2bf(s * hown[row * 32 + lc]);
      }
    }
    if (group_barrier(ctr, (++nbar) * 16, tid, &s_dead)) break;

    // ---- phase 2: h~ from (r*h), h update
    stage16x512(rh_buf, g, j, h_st, tid);
    __syncthreads();
    // prefetch next step's gates NOW (plain loads): they complete under the MFMA /
    // epilogue, so the pre-barrier vmcnt(0) and the poll carry no outstanding loads.
    if (tt + 1 < Tc) {
      const size_t gb = (size_t)((size_t)(tt + 1) * 256 + g * 16) * 1536;
#pragma unroll
      for (int q = 0; q < 4; ++q) {
        n1u[q] = gates[gb + (size_t)(l4 * 4 + q) * 1536 + (p1gate << 9) + colg1];
        n2u[q] = gates[gb + (size_t)(l4 * 4 + q) * 1536 + 1024 + colg2];
      }
    }
    {
      const ushort_t* ap = &h_st[l15 * 520 + p2kh * 256 + l4 * 8];
      f32x4 a0 = {0.f, 0.f, 0.f, 0.f}, a1 = {0.f, 0.f, 0.f, 0.f};
#pragma unroll
      for (int kk = 0; kk < 8; kk += 2) {
        a0 = __builtin_amdgcn_mfma_f32_16x16x32_bf16(*(const bf16x8*)(ap + kk * 32), UH[kk], a0, 0, 0, 0);
        a1 = __builtin_amdgcn_mfma_f32_16x16x32_bf16(*(const bf16x8*)(ap + kk * 32 + 32), UH[kk + 1], a1, 0, 0, 0);
      }
      const f32x4 acc = a0 + a1;
      if (p2kh == 1) {
#pragma unroll
        for (int q = 0; q < 4; ++q) red[p2nt * 256 + (l4 * 4 + q) * 16 + l15] = acc[q];
      }
      __syncthreads();
      if (p2kh == 0) {
        const int lc = p2nt * 16 + l15;
#pragma unroll
        for (int q = 0; q < 4; ++q) {
          const int row = l4 * 4 + q;
          const float dot = acc[q] + red[p2nt * 256 + row * 16 + l15];
          float pre = dot + bfu2f(c2u[q]);
          pre = fminf(15.f, fmaxf(-15.f, pre));
          const float e = __expf(2.f * pre);
          const float th = (e - 1.f) / (e + 1.f);
          const float z = z_sh[row * 32 + lc];
          const float hold = hown[row * 32 + lc];
          const float hnew = (1.f - z) * hold + z * th;
          hown[row * 32 + lc] = hnew;
          h_buf[((g * 16 + row) << 9) + j * 32 + lc] = f2bf(hnew);
          if (tt == Tc - 1) h_state[((g * 16 + row) << 9) + j * 32 + lc] = hnew;
        }
      }
    }
    if (group_barrier(ctr, (++nbar) * 16, tid, &s_dead)) break;
  }
}

// ---------------------------------------------------------------- FC
__global__ __launch_bounds__(256) void fc_kernel(
    const float* __restrict__ h, const float* __restrict__ Wfc,
    const float* __restrict__ bfc, float* __restrict__ logits)
{
  __shared__ float hsh[16][520];
  const int tid = threadIdx.x;
  const int by = blockIdx.y;
  {
    const int r = tid >> 4, seg = tid & 15;
    const float* src = &h[(size_t)(by * 16 + r) * 512 + seg * 32];
#pragma unroll
    for (int i = 0; i < 8; ++i) {
      float4 v = *(const float4*)&src[i * 4];
      v.x = fmaxf(v.x, 0.f); v.y = fmaxf(v.y, 0.f);
      v.z = fmaxf(v.z, 0.f); v.w = fmaxf(v.w, 0.f);
      *(float4*)&hsh[r][seg * 32 + i * 4] = v;
    }
  }
  __syncthreads();
  const int c = tid & 63, rq = tid >> 6;
  const int gc = blockIdx.x * 64 + c;
  if (gc >= 1000) return;
  float acc0 = 0.f, acc1 = 0.f, acc2 = 0.f, acc3 = 0.f;
  for (int k = 0; k < 512; ++k) {
    const float w = Wfc[(size_t)k * 1000 + gc];
    acc0 += hsh[rq * 4 + 0][k] * w;
    acc1 += hsh[rq * 4 + 1][k] * w;
    acc2 += hsh[rq * 4 + 2][k] * w;
    acc3 += hsh[rq * 4 + 3][k] * w;
  }
  const float bv = bfc[gc];
  const int r0 = by * 16 + rq * 4;
  logits[(size_t)(r0 + 0) * 1000 + gc] = acc0 + bv;
  logits[(size_t)(r0 + 1) * 1000 + gc] = acc1 + bv;
  logits[(size_t)(r0 + 2) * 1000 + gc] = acc2 + bv;
  logits[(size_t)(r0 + 3) * 1000 + gc] = acc3 + bv;
}

// ---------------------------------------------------------------- log_softmax over batch
__global__ __launch_bounds__(256) void lsm_kernel(const float* __restrict__ logits,
                                                  float* __restrict__ out)
{
  const int c = blockIdx.x, tid = threadIdx.x;
  const int wid = tid >> 6, lane = tid & 63;
  __shared__ float red[8];
  const float v = logits[(size_t)tid * 1000 + c];
  float m = v;
#pragma unroll
  for (int o = 32; o >= 1; o >>= 1) m = fmaxf(m, __shfl_xor(m, o));
  if (lane == 0) red[wid] = m;
  __syncthreads();
  m = fmaxf(fmaxf(red[0], red[1]), fmaxf(red[2], red[3]));
  float s = __expf(v - m);
#pragma unroll
  for (int o = 32; o >= 1; o >>= 1) s += __shfl_xor(s, o);
  if (lane == 0) red[4 + wid] = s;
  __syncthreads();
  s = red[4] + red[5] + red[6] + red[7];
  out[(size_t)tid * 1000 + c] = (v - m) - __logf(s);
}

// ---------------------------------------------------------------- launch
extern "C" void kernel_launch(void* const* d_in, const int* in_sizes, int n_in,
                              void* d_out, int out_size, void* d_ws, size_t ws_size,
                              hipStream_t stream) {
  (void)in_sizes; (void)n_in; (void)out_size;
  const float* x   = (const float*)d_in[0];
  const float* Wz  = (const float*)d_in[1];
  const float* bz  = (const float*)d_in[2];
  const float* Uz  = (const float*)d_in[3];
  const float* buz = (const float*)d_in[4];
  const float* Wr  = (const float*)d_in[5];
  const float* br  = (const float*)d_in[6];
  const float* Ur  = (const float*)d_in[7];
  const float* bur = (const float*)d_in[8];
  const float* Wh  = (const float*)d_in[9];
  const float* bh  = (const float*)d_in[10];
  const float* Uh  = (const float*)d_in[11];
  const float* buh = (const float*)d_in[12];
  const float* Wfc = (const float*)d_in[13];
  const float* bfc = (const float*)d_in[14];
  float* out = (float*)d_out;
  char* ws = (char*)d_ws;

  ushort_t* UT     = (ushort_t*)(ws + 0);        // 1572864 B
  ushort_t* WT     = (ushort_t*)(ws + 1572864);  // 1572864 B
  float*    gbias  = (float*)(ws + 3145728);     // 6144 B
  ushort_t* h_buf  = (ushort_t*)(ws + 3151872);  // 262144 B
  ushort_t* rh_buf = (ushort_t*)(ws + 3414016);  // 262144 B
  float*    hstate = (float*)(ws + 3676160);     // 524288 B
  float*    logits = (float*)(ws + 4200448);     // 1024000 B (256x1000)
  uint_t*   bars   = (uint_t*)(ws + 5224448);    // 4096 B (16 groups x 256B)
  ushort_t* gates  = (ushort_t*)(ws + 5228544);  // Tc*256*1536*2 B

  const size_t fixed = 5228544;
  const size_t per_step = (size_t)256 * 1536 * 2;
  int Tc_max = 2048;
  if (ws_size < fixed + (size_t)2048 * per_step) {
    const size_t avail = (ws_size > fixed) ? (ws_size - fixed) : 0;
    Tc_max = (int)(avail / per_step);
    Tc_max &= ~15;             // keep mtiles % 32 == 0 for the GEMM supertile swizzle
    if (Tc_max < 16) Tc_max = 16;
  }

  prep_kernel<<<3072, 256, 0, stream>>>(Wz, Wr, Wh, Uz, Ur, Uh,
                                        bz, buz, br, bur, bh, buh, UT, WT, gbias);

  int done = 0;
  while (done < 2048) {
    const int Tc = (2048 - done < Tc_max) ? (2048 - done) : Tc_max;
    const int mtiles = Tc * 2;  // Tc*256/128
    gate_gemm<<<mtiles * 12, 256, 0, stream>>>(x + (size_t)done * 256 * 512, WT, gbias, gates, mtiles);
    hipMemsetAsync(bars, 0, 4096, stream);
    gru_rec<<<256, 256, 0, stream>>>(UT, gates, h_buf, rh_buf, hstate, bars, Tc, done == 0 ? 1 : 0);
    done += Tc;
  }
  fc_kernel<<<dim3(16, 16), 256, 0, stream>>>(hstate, Wfc, bfc, logits);
  lsm_kernel<<<1000, 256, 0, stream>>>(logits, out);
}